// Round 15
// baseline (30.072 us; speedup 1.0000x reference)
//
#include <hip/hip_runtime.h>

#define BB 16
#define NN 100000
#define KK 8
#define BLOCK 256
#define BLOCK2 128

#define ROW_U4 4                              // fp8 row: 4 uint4 = 64B (48 data + 16B zero pad)
#define DT_BYTES ((size_t)NN * 64)            // 6.4 MB
#define GRID1 ((NN + 63) / 64)                // 1563 blocks, 64 vertices each
#define GRID2 (NN * 4 / BLOCK2)               // 3125 blocks (400k threads, one residency round)
#define NWAVE2 (NN * 4 / 64)                  // 6250 wave partials
#define SCALE (1.0f / ((float)BB * NN * 3))

typedef float f32x2 __attribute__((ext_vector_type(2)));

// pack 4 f32 -> 4 fp8 e4m3 (one dword) via HW converts
__device__ __forceinline__ unsigned pk_fp8x4(float a, float b, float c, float d) {
    int v = __builtin_amdgcn_cvt_pk_fp8_f32(a, b, 0, false);   // bytes 0,1
    v     = __builtin_amdgcn_cvt_pk_fp8_f32(c, d, v, true);    // bytes 2,3
    return (unsigned)v;
}

// a[0..15] += wv * unpack16_fp8(u)
__device__ __forceinline__ void fma16(float* a, uint4 u, float wv) {
    f32x2 p;
    p = __builtin_amdgcn_cvt_pk_f32_fp8((int)u.x, false); a[0]  += wv * p.x; a[1]  += wv * p.y;
    p = __builtin_amdgcn_cvt_pk_f32_fp8((int)u.x, true ); a[2]  += wv * p.x; a[3]  += wv * p.y;
    p = __builtin_amdgcn_cvt_pk_f32_fp8((int)u.y, false); a[4]  += wv * p.x; a[5]  += wv * p.y;
    p = __builtin_amdgcn_cvt_pk_f32_fp8((int)u.y, true ); a[6]  += wv * p.x; a[7]  += wv * p.y;
    p = __builtin_amdgcn_cvt_pk_f32_fp8((int)u.z, false); a[8]  += wv * p.x; a[9]  += wv * p.y;
    p = __builtin_amdgcn_cvt_pk_f32_fp8((int)u.z, true ); a[10] += wv * p.x; a[11] += wv * p.y;
    p = __builtin_amdgcn_cvt_pk_f32_fp8((int)u.w, false); a[12] += wv * p.x; a[13] += wv * p.y;
    p = __builtin_amdgcn_cvt_pk_f32_fp8((int)u.w, true ); a[14] += wv * p.x; a[15] += wv * p.y;
}

// ---------- Kernel 1: coalesced diff + LDS transpose + fp8 pack (64B rows) ----------
__global__ __launch_bounds__(BLOCK) void diff_transpose_fp8_kernel(
    const float4* __restrict__ geom4,
    const float4* __restrict__ gtp4,
    uint4*        __restrict__ dT4)
{
    __shared__ float tile[64][49];   // [vertex in block][b*3+c], +1 pad
    int tid = threadIdx.x;
    int b = tid >> 4;                // 0..15
    int q = tid & 15;                // n-quad within block
    int nbase = blockIdx.x * 64;
    int n0 = nbase + q * 4;

    if (n0 < NN) {
        int fi = (b * (NN * 3) + n0 * 3) >> 2;        // float4 index, coalesced
        float4 g0 = geom4[fi], g1 = geom4[fi + 1], g2 = geom4[fi + 2];
        float4 t0 = gtp4[fi],  t1 = gtp4[fi + 1],  t2 = gtp4[fi + 2];
        float d[12] = {g0.x - t0.x, g0.y - t0.y, g0.z - t0.z, g0.w - t0.w,
                       g1.x - t1.x, g1.y - t1.y, g1.z - t1.z, g1.w - t1.w,
                       g2.x - t2.x, g2.y - t2.y, g2.z - t2.z, g2.w - t2.w};
        #pragma unroll
        for (int e = 0; e < 12; ++e)
            tile[q * 4 + e / 3][b * 3 + e % 3] = d[e];
    }
    __syncthreads();

    // 64 rows x 4 uint4 per row = 256 fully-coalesced 16B stores (1 per thread)
    {
        int r = tid >> 2, m = tid & 3;       // m: which uint4 of the 64B row
        int n = nbase + r;
        if (n < NN) {
            uint4 o;
            if (m < 3) {
                const float* row = &tile[r][m * 16];
                o.x = pk_fp8x4(row[0],  row[1],  row[2],  row[3]);
                o.y = pk_fp8x4(row[4],  row[5],  row[6],  row[7]);
                o.z = pk_fp8x4(row[8],  row[9],  row[10], row[11]);
                o.w = pk_fp8x4(row[12], row[13], row[14], row[15]);
            } else {
                o.x = o.y = o.z = o.w = 0u;  // 16B zero pad
            }
            dT4[n * ROW_U4 + m] = o;
        }
    }
}

// ---------- Kernel 2: 4 threads/vertex, explicit 9-deep load batch ----------
// One residency round (400k threads). BLOCK2=128: 12.2 blocks/CU -> 6.5% tail
// imbalance (vs 15% at 256). All 9 gathers + idx/w issued before any VALU
// consumes them (explicit MLP, G7); launch_bounds(128,6) keeps VGPR<=85 so
// 24 waves/CU stay resident. Per-wave partial store: no LDS/syncthreads.
// NO atomics/fences (R4-R9 lesson).
__global__ __launch_bounds__(BLOCK2, 6) void lap_gather_kernel(
    const uint4* __restrict__ dv,
    const int*   __restrict__ idx,
    const float* __restrict__ w,
    float*       __restrict__ partial)
{
    int t = blockIdx.x * BLOCK2 + threadIdx.x;   // 400000 exact, no tail
    int n = t >> 2;
    int s = t & 3;                  // which uint4 of the 64B row (3 = pad)

    const int4*   ip = reinterpret_cast<const int4*>(idx + (size_t)n * KK);
    const float4* wp = reinterpret_cast<const float4*>(w + (size_t)n * KK);
    int4   i0 = ip[0], i1 = ip[1];             // broadcast across 4-lane group
    float4 w0 = wp[0], w1 = wp[1];

    // issue all 9 independent 16B gathers back-to-back (each quad = 1 full line)
    uint4 r0 = dv[i0.x * ROW_U4 + s];
    uint4 r1 = dv[i0.y * ROW_U4 + s];
    uint4 r2 = dv[i0.z * ROW_U4 + s];
    uint4 r3 = dv[i0.w * ROW_U4 + s];
    uint4 r4 = dv[i1.x * ROW_U4 + s];
    uint4 r5 = dv[i1.y * ROW_U4 + s];
    uint4 r6 = dv[i1.z * ROW_U4 + s];
    uint4 r7 = dv[i1.w * ROW_U4 + s];
    uint4 rs = dv[n    * ROW_U4 + s];

    float a[16];
    #pragma unroll
    for (int i = 0; i < 16; ++i) a[i] = 0.0f;

    fma16(a, r0, w0.x); fma16(a, r1, w0.y);
    fma16(a, r2, w0.z); fma16(a, r3, w0.w);
    fma16(a, r4, w1.x); fma16(a, r5, w1.y);
    fma16(a, r6, w1.z); fma16(a, r7, w1.w);
    fma16(a, rs, 1.0f);                        // self term

    float ssq = 0.0f;
    #pragma unroll
    for (int i = 0; i < 16; ++i) ssq += a[i] * a[i];

    #pragma unroll
    for (int off = 32; off > 0; off >>= 1)
        ssq += __shfl_down(ssq, off, 64);

    if ((threadIdx.x & 63) == 0)
        partial[t >> 6] = ssq;                 // one store per wave
}

// ---------- Kernel 3: final reduce of 6250 wave partials ----------
__global__ __launch_bounds__(1024) void final_reduce_kernel(
    const float* __restrict__ partial,
    float*       __restrict__ out)
{
    float s = 0.0f;
    for (int i = threadIdx.x; i < NWAVE2; i += 1024)
        s += partial[i];

    #pragma unroll
    for (int off = 32; off > 0; off >>= 1)
        s += __shfl_down(s, off, 64);

    __shared__ float wsum[1024 / 64];
    int lane = threadIdx.x & 63;
    int wid  = threadIdx.x >> 6;
    if (lane == 0) wsum[wid] = s;
    __syncthreads();

    if (threadIdx.x == 0) {
        float sum = 0.0f;
        #pragma unroll
        for (int i = 0; i < 1024 / 64; ++i) sum += wsum[i];
        out[0] = sum * SCALE;
    }
}

extern "C" void kernel_launch(void* const* d_in, const int* in_sizes, int n_in,
                              void* d_out, int out_size, void* d_ws, size_t ws_size,
                              hipStream_t stream) {
    const float* geom = (const float*)d_in[0];
    const float* gtp  = (const float*)d_in[1];
    const int*   idx  = (const int*)d_in[2];
    const float* w    = (const float*)d_in[3];
    float* out = (float*)d_out;

    uint4* dT4     = (uint4*)d_ws;
    float* partial = (float*)((char*)d_ws + DT_BYTES);

    diff_transpose_fp8_kernel<<<GRID1, BLOCK, 0, stream>>>(
        (const float4*)geom, (const float4*)gtp, dT4);
    lap_gather_kernel<<<GRID2, BLOCK2, 0, stream>>>(dT4, idx, w, partial);
    final_reduce_kernel<<<1, 1024, 0, stream>>>(partial, out);
}

// Round 16
// 26.478 us; speedup vs baseline: 1.1357x; 1.1357x over previous
//
#include <hip/hip_runtime.h>

#define BB 16
#define NN 100000
#define KK 8
#define BLOCK 256

#define ROW_U4 4                              // fp8 row: 4 uint4 = 64B (48 data + 16B zero pad)
#define DT_BYTES ((size_t)NN * 64)            // 6.4 MB
#define GRID1 ((NN + 63) / 64)                // 1563 blocks, 64 vertices each
#define GRID2 ((NN * 4 + BLOCK - 1) / BLOCK)  // 1563 blocks: 400k threads, ALL resident at once
#define SCALE (1.0f / ((float)BB * NN * 3))

typedef float f32x2 __attribute__((ext_vector_type(2)));

// pack 4 f32 -> 4 fp8 e4m3 (one dword) via HW converts
__device__ __forceinline__ unsigned pk_fp8x4(float a, float b, float c, float d) {
    int v = __builtin_amdgcn_cvt_pk_fp8_f32(a, b, 0, false);   // bytes 0,1
    v     = __builtin_amdgcn_cvt_pk_fp8_f32(c, d, v, true);    // bytes 2,3
    return (unsigned)v;
}

// a[0..15] += wv * unpack16_fp8(u)
__device__ __forceinline__ void fma16(float* a, uint4 u, float wv) {
    f32x2 p;
    p = __builtin_amdgcn_cvt_pk_f32_fp8((int)u.x, false); a[0]  += wv * p.x; a[1]  += wv * p.y;
    p = __builtin_amdgcn_cvt_pk_f32_fp8((int)u.x, true ); a[2]  += wv * p.x; a[3]  += wv * p.y;
    p = __builtin_amdgcn_cvt_pk_f32_fp8((int)u.y, false); a[4]  += wv * p.x; a[5]  += wv * p.y;
    p = __builtin_amdgcn_cvt_pk_f32_fp8((int)u.y, true ); a[6]  += wv * p.x; a[7]  += wv * p.y;
    p = __builtin_amdgcn_cvt_pk_f32_fp8((int)u.z, false); a[8]  += wv * p.x; a[9]  += wv * p.y;
    p = __builtin_amdgcn_cvt_pk_f32_fp8((int)u.z, true ); a[10] += wv * p.x; a[11] += wv * p.y;
    p = __builtin_amdgcn_cvt_pk_f32_fp8((int)u.w, false); a[12] += wv * p.x; a[13] += wv * p.y;
    p = __builtin_amdgcn_cvt_pk_f32_fp8((int)u.w, true ); a[14] += wv * p.x; a[15] += wv * p.y;
}

// ---------- Kernel 1: coalesced diff + LDS transpose + fp8 pack (64B rows) ----------
// dT[n][b*3+c] (fp8 e4m3, 48 data + 16 zero-pad bytes) = geom[b][n][c] - gtp[b][n][c]
__global__ __launch_bounds__(BLOCK) void diff_transpose_fp8_kernel(
    const float4* __restrict__ geom4,
    const float4* __restrict__ gtp4,
    uint4*        __restrict__ dT4)
{
    __shared__ float tile[64][49];   // [vertex in block][b*3+c], +1 pad
    int tid = threadIdx.x;
    int b = tid >> 4;                // 0..15
    int q = tid & 15;                // n-quad within block
    int nbase = blockIdx.x * 64;
    int n0 = nbase + q * 4;

    if (n0 < NN) {
        int fi = (b * (NN * 3) + n0 * 3) >> 2;        // float4 index, coalesced
        float4 g0 = geom4[fi], g1 = geom4[fi + 1], g2 = geom4[fi + 2];
        float4 t0 = gtp4[fi],  t1 = gtp4[fi + 1],  t2 = gtp4[fi + 2];
        float d[12] = {g0.x - t0.x, g0.y - t0.y, g0.z - t0.z, g0.w - t0.w,
                       g1.x - t1.x, g1.y - t1.y, g1.z - t1.z, g1.w - t1.w,
                       g2.x - t2.x, g2.y - t2.y, g2.z - t2.z, g2.w - t2.w};
        #pragma unroll
        for (int e = 0; e < 12; ++e)
            tile[q * 4 + e / 3][b * 3 + e % 3] = d[e];
    }
    __syncthreads();

    // 64 rows x 4 uint4 per row = 256 fully-coalesced 16B stores (1 per thread)
    {
        int r = tid >> 2, m = tid & 3;       // m: which uint4 of the 64B row
        int n = nbase + r;
        if (n < NN) {
            uint4 o;
            if (m < 3) {
                const float* row = &tile[r][m * 16];
                o.x = pk_fp8x4(row[0],  row[1],  row[2],  row[3]);
                o.y = pk_fp8x4(row[4],  row[5],  row[6],  row[7]);
                o.z = pk_fp8x4(row[8],  row[9],  row[10], row[11]);
                o.w = pk_fp8x4(row[12], row[13], row[14], row[15]);
            } else {
                o.x = o.y = o.z = o.w = 0u;  // 16B zero pad
            }
            dT4[n * ROW_U4 + m] = o;
        }
    }
}

// ---------- Kernel 2: 4 threads/vertex, 9 independent loads/thread ----------
// ONE residency round: 400k threads < 524k machine capacity -> every thread
// resident simultaneously, each with 9 outstanding 16B gathers = max MLP,
// single latency exposure. (R15 lesson: hand-batched loads + launch_bounds
// occupancy cap REGRESSED 26.6->30.1; let the compiler schedule.) Quad s=0..3
// covers the full aligned 64B row. Plain store; NO atomics/fences (R4-R9).
__global__ __launch_bounds__(BLOCK) void lap_gather_kernel(
    const uint4* __restrict__ dv,
    const int*   __restrict__ idx,
    const float* __restrict__ w,
    float*       __restrict__ partial)
{
    int t = blockIdx.x * BLOCK + threadIdx.x;
    int n = t >> 2;
    int s = t & 3;                  // which uint4 of the 64B row (3 = pad)

    float ssq = 0.0f;
    if (n < NN) {
        float a[16];
        #pragma unroll
        for (int i = 0; i < 16; ++i) a[i] = 0.0f;

        const int4*   ip = reinterpret_cast<const int4*>(idx + (size_t)n * KK);
        const float4* wp = reinterpret_cast<const float4*>(w + (size_t)n * KK);
        int4   i0 = ip[0], i1 = ip[1];             // broadcast across 4-lane group
        float4 w0 = wp[0], w1 = wp[1];
        int   js[KK] = {i0.x, i0.y, i0.z, i0.w, i1.x, i1.y, i1.z, i1.w};
        float wk[KK] = {w0.x, w0.y, w0.z, w0.w, w1.x, w1.y, w1.z, w1.w};

        // 8 neighbor gathers + self: 9 independent 16B loads, quad = 1 full line
        #pragma unroll
        for (int k = 0; k < KK; ++k)
            fma16(a, dv[js[k] * ROW_U4 + s], wk[k]);
        fma16(a, dv[n * ROW_U4 + s], 1.0f);

        #pragma unroll
        for (int i = 0; i < 16; ++i) ssq += a[i] * a[i];
    }

    #pragma unroll
    for (int off = 32; off > 0; off >>= 1)
        ssq += __shfl_down(ssq, off, 64);

    __shared__ float wsum[BLOCK / 64];
    int lane = threadIdx.x & 63;
    int wid  = threadIdx.x >> 6;
    if (lane == 0) wsum[wid] = ssq;
    __syncthreads();

    if (threadIdx.x == 0)
        partial[blockIdx.x] = wsum[0] + wsum[1] + wsum[2] + wsum[3];
}

// ---------- Kernel 3: tiny final reduce (1024 threads), overwrites out ----------
__global__ __launch_bounds__(1024) void final_reduce_kernel(
    const float* __restrict__ partial,
    float*       __restrict__ out)
{
    float s = 0.0f;
    for (int i = threadIdx.x; i < GRID2; i += 1024)
        s += partial[i];

    #pragma unroll
    for (int off = 32; off > 0; off >>= 1)
        s += __shfl_down(s, off, 64);

    __shared__ float wsum[1024 / 64];
    int lane = threadIdx.x & 63;
    int wid  = threadIdx.x >> 6;
    if (lane == 0) wsum[wid] = s;
    __syncthreads();

    if (threadIdx.x == 0) {
        float sum = 0.0f;
        #pragma unroll
        for (int i = 0; i < 1024 / 64; ++i) sum += wsum[i];
        out[0] = sum * SCALE;
    }
}

extern "C" void kernel_launch(void* const* d_in, const int* in_sizes, int n_in,
                              void* d_out, int out_size, void* d_ws, size_t ws_size,
                              hipStream_t stream) {
    const float* geom = (const float*)d_in[0];
    const float* gtp  = (const float*)d_in[1];
    const int*   idx  = (const int*)d_in[2];
    const float* w    = (const float*)d_in[3];
    float* out = (float*)d_out;

    uint4* dT4     = (uint4*)d_ws;
    float* partial = (float*)((char*)d_ws + DT_BYTES);

    diff_transpose_fp8_kernel<<<GRID1, BLOCK, 0, stream>>>(
        (const float4*)geom, (const float4*)gtp, dT4);
    lap_gather_kernel<<<GRID2, BLOCK, 0, stream>>>(dT4, idx, w, partial);
    final_reduce_kernel<<<1, 1024, 0, stream>>>(partial, out);
}